// Round 4
// baseline (364.569 us; speedup 1.0000x reference)
//
#include <hip/hip_runtime.h>
#include <math.h>

#define T_STEPS 256
#define Fdim 32
#define Udim 64
#define G4 256            // 4*U
#define OUT_STEPS 24
#define ROWS 16           // batch rows per block (= MFMA N)
#define NBLK 256          // 4096 / 16
#define NTHR 1024         // 16 waves, 4 waves/SIMD
#define HXS 104           // bf16 row stride (96 + 8 pad); stride/4 = 52 ≡ 4 (mod 8) -> 2-way (free) b128 reads
#define LOG2E 1.4426950408889634f

typedef __attribute__((ext_vector_type(8))) short short8;   // 8 bf16 = 4 VGPR
typedef __attribute__((ext_vector_type(4))) float f32x4;

__device__ __forceinline__ short f2bf(float f) {
    union { float f; unsigned u; } v; v.f = f;
    unsigned r = v.u + 0x7FFFu + ((v.u >> 16) & 1u);   // RNE
    return (short)(r >> 16);
}
__device__ __forceinline__ float bf2f(short s) {
    union { unsigned u; float f; } v; v.u = ((unsigned)(unsigned short)s) << 16;
    return v.f;
}
__device__ __forceinline__ float frcp(float v) { return __builtin_amdgcn_rcpf(v); }
__device__ __forceinline__ float fexp2(float v) { return __builtin_amdgcn_exp2f(v); }
// inputs pre-scaled by log2e: sigm(z) = rcp(1 + exp2(-s))
__device__ __forceinline__ float sigm2(float s) { return frcp(1.0f + fexp2(-s)); }
// input pre-scaled by 2*log2e: tanh(z) = 1 - 2*rcp(1 + exp2(s));  saturates correctly at +-inf
__device__ __forceinline__ float tanh2(float s) { return fmaf(-2.0f, frcp(1.0f + fexp2(s)), 1.0f); }

// z^T = Wt[256x96] @ hx^T[96x16], gate rows packed as r = unit*4 + gate.
// 16 waves, wave w owns tile w (gate-rows w*16..w*16+15).
// A-frag: lane l holds A[m=l&15][k=(l>>4)*8+j]  -> static pre-scaled weights in VGPRs
// B-frag: lane l holds B[k=(l>>4)*8+j][n=l&15]  -> hxb[m][k...] via ds_read_b128
// C/D:    lane l holds D[row=q*4+reg][col=m]    -> all 4 gates of cell (unit=w*4+q, batchrow=m)
__global__ __launch_bounds__(NTHR, 1)
void lstm_mfma_t4(const float* __restrict__ x,
                  const float* __restrict__ W1, const float* __restrict__ U1, const float* __restrict__ b1,
                  const float* __restrict__ W2, const float* __restrict__ U2, const float* __restrict__ b2,
                  const float* __restrict__ Wd, const float* __restrict__ bd,
                  float* __restrict__ out)
{
    __shared__ __align__(16) short hxb[2][ROWS][HXS]; // bf16 bits: [0..63]=h, [64..95]=x/pred (ping-pong)
    __shared__ float WdL[Udim * Fdim];                // dense weights, fp32

    const int tid = threadIdx.x;
    const int l   = tid & 63;         // lane
    const int w   = tid >> 6;         // wave 0..15 = gate-row tile
    const int q   = l >> 4;           // quad
    const int m   = l & 15;           // batch row (B col / D col)
    const int brow = blockIdx.x * ROWS;

    // ---- stage both weight sets as register-resident A-fragments, pre-scaled by log2e / 2log2e ----
    short8 wa1[3], wa2[3];
    float bs1[4], bs2[4];
    {
        const int grow = w * 16 + m;              // A-frag row m -> gate-row
        const int unit_a = grow >> 2;
        const int gate_a = grow & 3;
        const int col = gate_a * 64 + unit_a;     // column in original [4U] layout
        const float sA = (gate_a == 2) ? 2.0f * LOG2E : LOG2E;
#pragma unroll
        for (int kt = 0; kt < 3; ++kt) {
            short8 fa, fb;
#pragma unroll
            for (int j = 0; j < 8; ++j) {
                const int k = kt * 32 + q * 8 + j;
                float v1 = (k < Udim) ? U1[k * G4 + col] : W1[(k - Udim) * G4 + col];
                float v2 = (k < Udim) ? U2[k * G4 + col] : W2[(k - Udim) * G4 + col];
                fa[j] = f2bf(v1 * sA);
                fb[j] = f2bf(v2 * sA);
            }
            wa1[kt] = fa;
            wa2[kt] = fb;
        }
        const int unit_d = w * 4 + q;             // D rows q*4+reg -> unit_d, gate=reg
#pragma unroll
        for (int g = 0; g < 4; ++g) {
            const float sD = (g == 2) ? 2.0f * LOG2E : LOG2E;
            bs1[g] = b1[g * 64 + unit_d] * sD;
            bs2[g] = b2[g * 64 + unit_d] * sD;
        }
    }

    // staging / dense ownership (first 512 threads): one (row, col) each
    const int sr = tid >> 5;          // 0..31 (valid < 16)
    const int sc = tid & 31;
    const float bdv = bd[sc];

    for (int idx = tid; idx < Udim * Fdim; idx += NTHR) WdL[idx] = Wd[idx];
    hxb[0][w][l] = 0;                 // h init: 16 rows x 64 units, one short per thread
    if (sr < ROWS)
        hxb[0][sr][Udim + sc] = f2bf(x[(size_t)(brow + sr) * (T_STEPS * Fdim) + sc]);
    float cst = 0.f;                  // fp32 cell state for (unit=w*4+q, row=m)
    const int hcol = w * 4 + q;       // h write column
    __syncthreads();

    const size_t xbase = (size_t)(brow + sr) * (T_STEPS * Fdim) + sc;

    // ================= warmup: 256 steps of LSTM1, 1 barrier/step =================
#pragma unroll 2
    for (int t = 0; t < T_STEPS; ++t) {
        const int p = t & 1;
        float xp = 0.f;
        if (t + 1 < T_STEPS && sr < ROWS)
            xp = x[xbase + (size_t)(t + 1) * Fdim];     // prefetch next x

        short8 bfv[3];
#pragma unroll
        for (int kt = 0; kt < 3; ++kt)
            bfv[kt] = *(const short8*)&hxb[p][m][kt * 32 + q * 8];

        f32x4 acc;
#pragma unroll
        for (int g = 0; g < 4; ++g) acc[g] = bs1[g];
#pragma unroll
        for (int kt = 0; kt < 3; ++kt)
            acc = __builtin_amdgcn_mfma_f32_16x16x32_bf16(wa1[kt], bfv[kt], acc, 0, 0, 0);

        float ig = sigm2(acc[0]);
        float fg = sigm2(acc[1]);
        float gg = tanh2(acc[2]);
        float og = sigm2(acc[3]);
        cst = fmaf(fg, cst, ig * gg);
        float hn = og * tanh2(2.0f * LOG2E * cst);
        hxb[1 - p][m][hcol] = f2bf(hn);
        if (t + 1 < T_STEPS && sr < ROWS)
            hxb[1 - p][sr][Udim + sc] = f2bf(xp);
        __syncthreads();
    }

    // ================= pred0 = h @ Wd + bd (h in buf0) =================
    if (sr < ROWS) {
        float acc = bdv;
#pragma unroll
        for (int kb = 0; kb < 8; ++kb) {
            short8 h8 = *(const short8*)&hxb[0][sr][kb * 8];
#pragma unroll
            for (int j = 0; j < 8; ++j)
                acc = fmaf(bf2f(h8[j]), WdL[(kb * 8 + j) * Fdim + sc], acc);
        }
        out[(size_t)(brow + sr) * (OUT_STEPS * Fdim) + sc] = acc;
        hxb[0][sr][Udim + sc] = f2bf(acc);   // x-part write, disjoint from h-part reads above
    }
    __syncthreads();

    // ================= decode: 23 steps of LSTM2 + dense =================
    int dp = 0;
    for (int s = 1; s < OUT_STEPS; ++s) {
        short8 bfv[3];
#pragma unroll
        for (int kt = 0; kt < 3; ++kt)
            bfv[kt] = *(const short8*)&hxb[dp][m][kt * 32 + q * 8];

        f32x4 acc;
#pragma unroll
        for (int g = 0; g < 4; ++g) acc[g] = bs2[g];
#pragma unroll
        for (int kt = 0; kt < 3; ++kt)
            acc = __builtin_amdgcn_mfma_f32_16x16x32_bf16(wa2[kt], bfv[kt], acc, 0, 0, 0);

        float ig = sigm2(acc[0]);
        float fg = sigm2(acc[1]);
        float gg = tanh2(acc[2]);
        float og = sigm2(acc[3]);
        cst = fmaf(fg, cst, ig * gg);
        float hn = og * tanh2(2.0f * LOG2E * cst);
        hxb[1 - dp][m][hcol] = f2bf(hn);
        __syncthreads();              // h ready for dense

        if (sr < ROWS) {
            float dacc = bdv;
#pragma unroll
            for (int kb = 0; kb < 8; ++kb) {
                short8 h8 = *(const short8*)&hxb[1 - dp][sr][kb * 8];
#pragma unroll
                for (int j = 0; j < 8; ++j)
                    dacc = fmaf(bf2f(h8[j]), WdL[(kb * 8 + j) * Fdim + sc], dacc);
            }
            out[(size_t)(brow + sr) * (OUT_STEPS * Fdim) + s * Fdim + sc] = dacc;
            hxb[1 - dp][sr][Udim + sc] = f2bf(dacc);  // pred feedback
        }
        __syncthreads();
        dp = 1 - dp;
    }
}

extern "C" void kernel_launch(void* const* d_in, const int* in_sizes, int n_in,
                              void* d_out, int out_size, void* d_ws, size_t ws_size,
                              hipStream_t stream) {
    (void)in_sizes; (void)n_in; (void)out_size; (void)d_ws; (void)ws_size;
    const float* x  = (const float*)d_in[0];
    const float* W1 = (const float*)d_in[1];
    const float* U1 = (const float*)d_in[2];
    const float* b1 = (const float*)d_in[3];
    const float* W2 = (const float*)d_in[4];
    const float* U2 = (const float*)d_in[5];
    const float* b2 = (const float*)d_in[6];
    const float* Wd = (const float*)d_in[7];
    const float* bd = (const float*)d_in[8];
    float* out = (float*)d_out;

    lstm_mfma_t4<<<dim3(NBLK), dim3(NTHR), 0, stream>>>(
        x, W1, U1, b1, W2, U2, b2, Wd, bd, out);
}

// Round 5
// 347.772 us; speedup vs baseline: 1.0483x; 1.0483x over previous
//
#include <hip/hip_runtime.h>
#include <math.h>

#define T_STEPS 256
#define Fdim 32
#define Udim 64
#define G4 256            // 4*U
#define OUT_STEPS 24
#define ROWS 16           // batch rows per block (= MFMA N)
#define NBLK 256          // 4096 / 16
#define NTHR 512          // 8 waves, 2 waves/SIMD
#define HBS 72            // hb row stride in shorts (144 B = 16B-aligned, bank-even for b128)
#define XPS 520           // xs plane stride in shorts (1040 B = 16B-aligned, bank-even)
#define CHUNK 32
#define NCHUNK 8          // 8 * 32 = 256 steps
#define LOG2E 1.4426950408889634f

typedef __attribute__((ext_vector_type(8))) short short8;   // 8 bf16 = 4 VGPR
typedef __attribute__((ext_vector_type(4))) float f32x4;

__device__ __forceinline__ short f2bf(float f) {
    union { float f; unsigned u; } v; v.f = f;
    unsigned r = v.u + 0x7FFFu + ((v.u >> 16) & 1u);   // RNE
    return (short)(r >> 16);
}
__device__ __forceinline__ float bf2f(short s) {
    union { unsigned u; float f; } v; v.u = ((unsigned)(unsigned short)s) << 16;
    return v.f;
}
__device__ __forceinline__ float frcp(float v) { return __builtin_amdgcn_rcpf(v); }
__device__ __forceinline__ float fexp2(float v) { return __builtin_amdgcn_exp2f(v); }
// weights pre-scaled by log2e: sigm(z) = rcp(1 + exp2(-s)); overflow-safe (inf -> rcp -> 0)
__device__ __forceinline__ float sigm2(float s) { return frcp(1.0f + fexp2(-s)); }
// weight pre-scaled by 2*log2e: tanh(z) = 1 - 2*rcp(1 + exp2(s)); saturates safely at +-inf
__device__ __forceinline__ float tanh2(float s) { return fmaf(-2.0f, frcp(1.0f + fexp2(s)), 1.0f); }

// z^T = Wt[256 gate-rows x 96] @ hx^T[96 x 16 rows], tile t covers gate-rows t*16..t*16+15.
// Gate-row packing within tile t, local row r = q*4+g:  unit = (t>>1)*8 + q*2 + (t&1), gate = g.
// Wave w (0..7) owns tiles 2w, 2w+1 -> lane (q,m) owns cells (units w*8+q*2, w*8+q*2+1; batch row m)
// => the two h outputs are ADJACENT units: one packed b32 LDS write.
// A-frag: lane l holds A[m=l&15][k=(l>>4)*8+j] (static pre-scaled weights in VGPRs)
// B-frag: lane l holds B[k=(l>>4)*8+j][n=l&15] (hb/xs reads, bank-even b128)
// C/D:    lane l holds D[row=q*4+reg][col=m]   (4 gates of one cell per lane)
__global__ __launch_bounds__(NTHR, 1)
void lstm_v5(const float* __restrict__ x,
             const float* __restrict__ W1, const float* __restrict__ U1, const float* __restrict__ b1,
             const float* __restrict__ W2, const float* __restrict__ U2, const float* __restrict__ b2,
             const float* __restrict__ Wd, const float* __restrict__ bd,
             float* __restrict__ out)
{
    __shared__ __align__(16) short hb[2][ROWS][HBS];     // bf16 h, ping-pong
    __shared__ __align__(16) short xs[CHUNK * XPS];      // bf16 x chunk; plane 0 reused for preds in decode
    __shared__ float WdL[Udim * Fdim];                   // dense weights, fp32

    const int tid = threadIdx.x;
    const int l   = tid & 63;
    const int w   = tid >> 6;         // wave 0..7
    const int q   = l >> 4;
    const int m   = l & 15;
    const int brow = blockIdx.x * ROWS;

    // ---- stage both weight sets as register-resident A-fragments (pre-scaled) ----
    short8 wa1[2][3], wa2[2][3];
    f32x4 bs1[2], bs2[2];
#pragma unroll
    for (int nt = 0; nt < 2; ++nt) {
        const int t = 2 * w + nt;
        const int unit_a = w * 8 + (m >> 2) * 2 + nt;  // A-row m -> (unit, gate)
        const int gate_a = m & 3;
        const int col = gate_a * 64 + unit_a;          // column in original [4U] layout
        const float sA = (gate_a == 2) ? 2.0f * LOG2E : LOG2E;
        (void)t;
#pragma unroll
        for (int kt = 0; kt < 3; ++kt) {
            short8 fa, fb;
#pragma unroll
            for (int j = 0; j < 8; ++j) {
                const int k = kt * 32 + q * 8 + j;
                float v1 = (k < Udim) ? U1[k * G4 + col] : W1[(k - Udim) * G4 + col];
                float v2 = (k < Udim) ? U2[k * G4 + col] : W2[(k - Udim) * G4 + col];
                fa[j] = f2bf(v1 * sA);
                fb[j] = f2bf(v2 * sA);
            }
            wa1[nt][kt] = fa;
            wa2[nt][kt] = fb;
        }
        const int unit_d = w * 8 + q * 2 + nt;         // D rows q*4+g -> unit_d, gate=g
#pragma unroll
        for (int g = 0; g < 4; ++g) {
            const float sD = (g == 2) ? 2.0f * LOG2E : LOG2E;
            bs1[nt][g] = b1[g * 64 + unit_d] * sD;
            bs2[nt][g] = b2[g * 64 + unit_d] * sD;
        }
    }

    const int sr = tid >> 5;          // dense/pred ownership: 0..15
    const int sc = tid & 31;
    const float bdv = bd[sc];
    const int hw = w * 8 + q * 2;     // packed h write index (even)

    for (int idx = tid; idx < 2 * ROWS * HBS; idx += NTHR) ((short*)hb)[idx] = 0;
    for (int idx = tid; idx < Udim * Fdim; idx += NTHR) WdL[idx] = Wd[idx];
    float cst[2] = {0.f, 0.f};

    // ================= warmup: 8 chunks x 32 steps, 1 barrier/step =================
    for (int c = 0; c < NCHUNK; ++c) {
        // stage chunk c of x as bf16 (coalesced 1KB/wave float4 loads; bank-even b64 writes)
#pragma unroll
        for (int i = 0; i < 8; ++i) {
            const int f4id = tid + i * NTHR;          // 0..4095
            const int row = f4id >> 8;
            const int tt  = (f4id >> 3) & 31;
            const int f4  = f4id & 7;
            const float4 v = *(const float4*)&x[((size_t)(brow + row) * T_STEPS + (c * CHUNK + tt)) * Fdim + f4 * 4];
            uint2 pk;
            pk.x = ((unsigned)(unsigned short)f2bf(v.y) << 16) | (unsigned short)f2bf(v.x);
            pk.y = ((unsigned)(unsigned short)f2bf(v.w) << 16) | (unsigned short)f2bf(v.z);
            *(uint2*)&xs[tt * XPS + row * 32 + f4 * 4] = pk;
        }
        __syncthreads();              // xs (and, for c=0, hb-init) visible

#pragma unroll 2
        for (int t2 = 0; t2 < CHUNK; ++t2) {
            const int p = t2 & 1;     // c*32 even -> parity continues across chunks

            const short8 b0 = *(const short8*)&hb[p][m][q * 8];
            const short8 b1v = *(const short8*)&hb[p][m][32 + q * 8];
            const short8 b2v = *(const short8*)&xs[t2 * XPS + m * 32 + q * 8];

            f32x4 a0 = __builtin_amdgcn_mfma_f32_16x16x32_bf16(wa1[0][0], b0, bs1[0], 0, 0, 0);
            f32x4 a1 = __builtin_amdgcn_mfma_f32_16x16x32_bf16(wa1[1][0], b0, bs1[1], 0, 0, 0);
            a0 = __builtin_amdgcn_mfma_f32_16x16x32_bf16(wa1[0][1], b1v, a0, 0, 0, 0);
            a1 = __builtin_amdgcn_mfma_f32_16x16x32_bf16(wa1[1][1], b1v, a1, 0, 0, 0);
            a0 = __builtin_amdgcn_mfma_f32_16x16x32_bf16(wa1[0][2], b2v, a0, 0, 0, 0);
            a1 = __builtin_amdgcn_mfma_f32_16x16x32_bf16(wa1[1][2], b2v, a1, 0, 0, 0);

            float hn[2];
            {
                float ig = sigm2(a0[0]), fg = sigm2(a0[1]);
                float gg = tanh2(a0[2]), og = sigm2(a0[3]);
                cst[0] = fmaf(fg, cst[0], ig * gg);
                hn[0] = og * tanh2(2.0f * LOG2E * cst[0]);
            }
            {
                float ig = sigm2(a1[0]), fg = sigm2(a1[1]);
                float gg = tanh2(a1[2]), og = sigm2(a1[3]);
                cst[1] = fmaf(fg, cst[1], ig * gg);
                hn[1] = og * tanh2(2.0f * LOG2E * cst[1]);
            }
            const unsigned ph = ((unsigned)(unsigned short)f2bf(hn[1]) << 16) | (unsigned short)f2bf(hn[0]);
            *(unsigned*)&hb[1 - p][m][hw] = ph;
            __syncthreads();          // doubles as pre-stage barrier for next chunk
        }
    }

    // ================= pred0 = h @ Wd + bd (h in hb[0]) =================
    {
        float acc = bdv;
#pragma unroll
        for (int kb = 0; kb < 8; ++kb) {
            short8 h8 = *(const short8*)&hb[0][sr][kb * 8];
#pragma unroll
            for (int j = 0; j < 8; ++j)
                acc = fmaf(bf2f(h8[j]), WdL[(kb * 8 + j) * Fdim + sc], acc);
        }
        out[(size_t)(brow + sr) * (OUT_STEPS * Fdim) + sc] = acc;
        xs[sr * 32 + sc] = f2bf(acc);     // pred buffer = xs plane 0
    }
    __syncthreads();

    // ================= decode: 23 steps of LSTM2 + dense =================
    int dp = 0;
    for (int s = 1; s < OUT_STEPS; ++s) {
        const short8 b0 = *(const short8*)&hb[dp][m][q * 8];
        const short8 b1v = *(const short8*)&hb[dp][m][32 + q * 8];
        const short8 b2v = *(const short8*)&xs[m * 32 + q * 8];

        f32x4 a0 = __builtin_amdgcn_mfma_f32_16x16x32_bf16(wa2[0][0], b0, bs2[0], 0, 0, 0);
        f32x4 a1 = __builtin_amdgcn_mfma_f32_16x16x32_bf16(wa2[1][0], b0, bs2[1], 0, 0, 0);
        a0 = __builtin_amdgcn_mfma_f32_16x16x32_bf16(wa2[0][1], b1v, a0, 0, 0, 0);
        a1 = __builtin_amdgcn_mfma_f32_16x16x32_bf16(wa2[1][1], b1v, a1, 0, 0, 0);
        a0 = __builtin_amdgcn_mfma_f32_16x16x32_bf16(wa2[0][2], b2v, a0, 0, 0, 0);
        a1 = __builtin_amdgcn_mfma_f32_16x16x32_bf16(wa2[1][2], b2v, a1, 0, 0, 0);

        float hn[2];
        {
            float ig = sigm2(a0[0]), fg = sigm2(a0[1]);
            float gg = tanh2(a0[2]), og = sigm2(a0[3]);
            cst[0] = fmaf(fg, cst[0], ig * gg);
            hn[0] = og * tanh2(2.0f * LOG2E * cst[0]);
        }
        {
            float ig = sigm2(a1[0]), fg = sigm2(a1[1]);
            float gg = tanh2(a1[2]), og = sigm2(a1[3]);
            cst[1] = fmaf(fg, cst[1], ig * gg);
            hn[1] = og * tanh2(2.0f * LOG2E * cst[1]);
        }
        const unsigned ph = ((unsigned)(unsigned short)f2bf(hn[1]) << 16) | (unsigned short)f2bf(hn[0]);
        *(unsigned*)&hb[1 - dp][m][hw] = ph;
        __syncthreads();              // h ready for dense

        float dacc = bdv;
#pragma unroll
        for (int kb = 0; kb < 8; ++kb) {
            short8 h8 = *(const short8*)&hb[1 - dp][sr][kb * 8];
#pragma unroll
            for (int j = 0; j < 8; ++j)
                dacc = fmaf(bf2f(h8[j]), WdL[(kb * 8 + j) * Fdim + sc], dacc);
        }
        out[(size_t)(brow + sr) * (OUT_STEPS * Fdim) + s * Fdim + sc] = dacc;
        xs[sr * 32 + sc] = f2bf(dacc);    // pred feedback
        __syncthreads();
        dp = 1 - dp;
    }
}

extern "C" void kernel_launch(void* const* d_in, const int* in_sizes, int n_in,
                              void* d_out, int out_size, void* d_ws, size_t ws_size,
                              hipStream_t stream) {
    (void)in_sizes; (void)n_in; (void)out_size; (void)d_ws; (void)ws_size;
    const float* x  = (const float*)d_in[0];
    const float* W1 = (const float*)d_in[1];
    const float* U1 = (const float*)d_in[2];
    const float* b1 = (const float*)d_in[3];
    const float* W2 = (const float*)d_in[4];
    const float* U2 = (const float*)d_in[5];
    const float* b2 = (const float*)d_in[6];
    const float* Wd = (const float*)d_in[7];
    const float* bd = (const float*)d_in[8];
    float* out = (float*)d_out;

    lstm_v5<<<dim3(NBLK), dim3(NTHR), 0, stream>>>(
        x, W1, U1, b1, W2, U2, b2, Wd, bd, out);
}